// Round 17
// baseline (181.645 us; speedup 1.0000x reference)
//
#include <hip/hip_runtime.h>
#include <type_traits>

#define NN 50000
#define NE 600000
#define FEAT 128
#define HID 256
#define MAXD 64   // ELL width; max in-degree of Poisson(12) over 50k nodes ~35

typedef float v4f __attribute__((ext_vector_type(4)));
typedef float f32x4 __attribute__((ext_vector_type(4)));
typedef __bf16 bf16x8 __attribute__((ext_vector_type(8)));
using u16 = unsigned short;
using u32 = unsigned int;
typedef u16 u16x4 __attribute__((ext_vector_type(4)));
typedef u16 u16x8 __attribute__((ext_vector_type(8)));

__device__ __forceinline__ u16 f2bf(float f) {
    u32 u = __builtin_bit_cast(u32, f);
    u += 0x7fffu + ((u >> 16) & 1u);   // RNE
    return (u16)(u >> 16);
}
__device__ __forceinline__ float bf2f(u16 h) {
    u32 u = ((u32)h) << 16;
    return __builtin_bit_cast(float, u);
}

// ------- merged prep: ELL fill (int, 1 edge/thr — r15 proven) + feats cvt + W1^T -------
#define NB_FILL 2344          // (NE+255)/256
#define NB_CVT 6250           // NN*FEAT/4/256
#define NB_W1  128
__global__ __launch_bounds__(256) void prep_fill_k(const int* __restrict__ src,
                                                   const int* __restrict__ dst,
                                                   int* __restrict__ cnt,
                                                   int* __restrict__ ell,
                                                   const float* __restrict__ feats,
                                                   const float* __restrict__ W1,
                                                   u16* __restrict__ featsbf,
                                                   u16* __restrict__ WT1) {
    int b = blockIdx.x, t = threadIdx.x;
    if (b < NB_FILL) {
        int e = b * 256 + t;
        if (e < NE) {
            int d = dst[e];
            int p = atomicAdd(&cnt[d], 1);
            if (p < MAXD) ell[(size_t)d * MAXD + p] = src[e];
        }
        return;
    }
    b -= NB_FILL;
    if (b < NB_CVT) {
        int i = b * 256 + t;
        v4f v = *(const v4f*)(feats + (size_t)i * 4);
        u16x4 o;
        #pragma unroll
        for (int j = 0; j < 4; j++) o[j] = f2bf(v[j]);
        *(u16x4*)(featsbf + (size_t)i * 4) = o;
    } else {
        int idx = (b - NB_CVT) * 256 + t;
        int k = idx >> 8, n = idx & 255;
        WT1[(size_t)n * 128 + k] = f2bf(W1[idx]);
    }
}

// ------- W23 = W2@Wd1 (bf16, transposed out) + c23 = b2@Wd1 -------
// 64 blocks x 4 k-rows; W2 rows in LDS; Wd1 read coalesced once per block.
__global__ __launch_bounds__(256) void w23_k(const float* __restrict__ W2,
                                             const float* __restrict__ Wd1,
                                             const float* __restrict__ b2,
                                             u16* __restrict__ WT23,
                                             float* __restrict__ c23) {
    __shared__ float w2s[4][256];
    int t = threadIdx.x;
    int k0 = blockIdx.x * 4;
    #pragma unroll
    for (int r = 0; r < 4; r++) w2s[r][t] = W2[(size_t)(k0 + r) * 256 + t];
    __syncthreads();
    float acc[4] = {0.f, 0.f, 0.f, 0.f};
    float accc = 0.f;
    bool doC = (blockIdx.x == 0);
    #pragma unroll 4
    for (int j = 0; j < 256; j++) {
        float w = Wd1[(size_t)j * 256 + t];
        #pragma unroll
        for (int r = 0; r < 4; r++) acc[r] += w2s[r][j] * w;
        if (doC) accc += b2[j] * w;
    }
    #pragma unroll
    for (int r = 0; r < 4; r++) WT23[(size_t)t * 256 + k0 + r] = f2bf(acc[r]);
    if (doC) c23[t] = accc;
}

// ------- agg1 (proven gather core, int ELL indexing) -------
template <int D>
__global__ __launch_bounds__(256) void aggregate_bf_k(const u16* __restrict__ x,
                                                      const int* __restrict__ cnt,
                                                      const int* __restrict__ ell,
                                                      u16* __restrict__ o) {
    constexpr int LPG = (D == 256) ? 32 : 16;
    constexpr int G = 64 / LPG;
    int wave = threadIdx.x >> 6;
    int lane = threadIdx.x & 63;
    int v = blockIdx.x * 4 + wave;
    if (v >= NN) return;
    int g  = lane / LPG;
    int li = lane & (LPG - 1);
    size_t coff = (size_t)li * 8;
    int deg = cnt[v]; if (deg > MAXD) deg = MAXD;
    int cntv = deg + 1;
    const int* cols = ell + (size_t)v * MAXD;
    float acc[8];
    #pragma unroll
    for (int i = 0; i < 8; i++) acc[i] = 0.f;
    int base = 0;
    #pragma unroll 4
    for (; base + G <= cntv; base += G) {
        int idx = base + g;
        int row = (idx < deg) ? cols[idx] : v;
        u16x8 r = *(const u16x8*)(x + (size_t)row * D + coff);
        #pragma unroll
        for (int i = 0; i < 8; i++) acc[i] += bf2f(r[i]);
    }
    if (base + g < cntv) {
        int idx = base + g;
        int row = (idx < deg) ? cols[idx] : v;
        u16x8 r = *(const u16x8*)(x + (size_t)row * D + coff);
        #pragma unroll
        for (int i = 0; i < 8; i++) acc[i] += bf2f(r[i]);
    }
    #pragma unroll
    for (int i = 0; i < 8; i++) {
        acc[i] += __shfl_xor(acc[i], 32, 64);
        if (G == 4) acc[i] += __shfl_xor(acc[i], 16, 64);
    }
    if (lane < LPG) {
        float inv = 1.0f / (float)cntv;
        u16x8 O;
        #pragma unroll
        for (int i = 0; i < 8; i++) O[i] = f2bf(acc[i] * inv);
        *(u16x8*)(o + (size_t)v * D + coff) = O;
    }
}

// ------- agg2 + full decoder epilogue (per-wave, no barrier, no MFMA) -------
// Z = H1@W23 + c23 precomputed; out[v] = relu(agg(Z)[v] + bd1) . wd2 + bd2.
__global__ __launch_bounds__(256) void agg2_dec_k(const u16* __restrict__ x,  // Z bf16
                                                  const int* __restrict__ cnt,
                                                  const int* __restrict__ ell,
                                                  const float* __restrict__ bd1,
                                                  const float* __restrict__ wd2,
                                                  const float* __restrict__ bd2,
                                                  float* __restrict__ out) {
    int wave = threadIdx.x >> 6;
    int lane = threadIdx.x & 63;
    int v = blockIdx.x * 4 + wave;
    if (v >= NN) return;
    int g  = lane >> 5;          // 2 edges in flight
    int li = lane & 31;
    size_t coff = (size_t)li * 8;
    int deg = cnt[v]; if (deg > MAXD) deg = MAXD;
    int cntv = deg + 1;
    const int* cols = ell + (size_t)v * MAXD;
    float acc[8];
    #pragma unroll
    for (int i = 0; i < 8; i++) acc[i] = 0.f;
    int base = 0;
    #pragma unroll 4
    for (; base + 2 <= cntv; base += 2) {
        int idx = base + g;
        int row = (idx < deg) ? cols[idx] : v;
        u16x8 r = *(const u16x8*)(x + (size_t)row * 256 + coff);
        #pragma unroll
        for (int i = 0; i < 8; i++) acc[i] += bf2f(r[i]);
    }
    if (base + g < cntv) {
        int idx = base + g;
        int row = (idx < deg) ? cols[idx] : v;
        u16x8 r = *(const u16x8*)(x + (size_t)row * 256 + coff);
        #pragma unroll
        for (int i = 0; i < 8; i++) acc[i] += bf2f(r[i]);
    }
    #pragma unroll
    for (int i = 0; i < 8; i++) acc[i] += __shfl_xor(acc[i], 32, 64);

    float inv = 1.0f / (float)cntv;
    v4f b0 = *(const v4f*)(bd1 + li * 8);
    v4f b1 = *(const v4f*)(bd1 + li * 8 + 4);
    v4f w0 = *(const v4f*)(wd2 + li * 8);
    v4f w1 = *(const v4f*)(wd2 + li * 8 + 4);
    float p = 0.f;
    #pragma unroll
    for (int i = 0; i < 4; i++) p += fmaxf(acc[i] * inv + b0[i], 0.f) * w0[i];
    #pragma unroll
    for (int i = 0; i < 4; i++) p += fmaxf(acc[i + 4] * inv + b1[i], 0.f) * w1[i];
    p += __shfl_xor(p, 1, 64);
    p += __shfl_xor(p, 2, 64);
    p += __shfl_xor(p, 4, 64);
    p += __shfl_xor(p, 8, 64);
    p += __shfl_xor(p, 16, 64);
    if (lane == 0) out[v] = p + bd2[0];
}

#define MFMA_BF16 __builtin_amdgcn_mfma_f32_16x16x32_bf16
#define SW(s, r) (((s) ^ (((r) >> 1) & 3)) * 8)

#define MFMA_STEP(pa0, pa1, pa2, pa3, ph0, ph1)              \
    do {                                                     \
        acc[0][0] = MFMA_BF16(pa0, ph0, acc[0][0], 0, 0, 0); \
        acc[0][1] = MFMA_BF16(pa0, ph1, acc[0][1], 0, 0, 0); \
        acc[1][0] = MFMA_BF16(pa1, ph0, acc[1][0], 0, 0, 0); \
        acc[1][1] = MFMA_BF16(pa1, ph1, acc[1][1], 0, 0, 0); \
        acc[2][0] = MFMA_BF16(pa2, ph0, acc[2][0], 0, 0, 0); \
        acc[2][1] = MFMA_BF16(pa2, ph1, acc[2][1], 0, 0, 0); \
        acc[3][0] = MFMA_BF16(pa3, ph0, acc[3][0], 0, 0, 0); \
        acc[3][1] = MFMA_BF16(pa3, ph1, acc[3][1], 0, 0, 0); \
    } while (0)

// ------- FUSED gemm1+gemm23: Z = relu(A1@W1+b1) @ W23 + c23 (bf16 out) -------
// BM=64, 512 thr = 8 waves over N=256 (wave 64x32). reg-dbuf staging both phases.
__global__ __launch_bounds__(512, 4) void fused_gemm12_k(const u16* __restrict__ A1,
                                                         const u16* __restrict__ B1,
                                                         const float* __restrict__ b1,
                                                         const u16* __restrict__ B23,
                                                         const float* __restrict__ c23,
                                                         u16* __restrict__ Z, int M) {
    __shared__ __attribute__((aligned(16))) u16 sA[2][64 * 32];
    __shared__ __attribute__((aligned(16))) u16 sB[2][256 * 32];
    __shared__ __attribute__((aligned(16))) u16 sH[64 * 264];

    int tid = threadIdx.x;
    int wid = tid >> 6, lane = tid & 63;
    int m0 = blockIdx.x * 64;
    int r16 = lane & 15, sl = lane >> 4, k8 = sl * 8;

    u32 ao[4], bo[2];
    #pragma unroll
    for (int mf = 0; mf < 4; mf++) {
        int ar = mf * 16 + r16;
        ao[mf] = ar * 32 + SW(sl, ar);
    }
    #pragma unroll
    for (int nf = 0; nf < 2; nf++) {
        int bc = wid * 32 + nf * 16 + r16;
        bo[nf] = bc * 32 + SW(sl, bc);
    }

    f32x4 acc[4][2];
    #pragma unroll
    for (int a = 0; a < 4; a++)
        #pragma unroll
        for (int b = 0; b < 2; b++) acc[a][b] = (f32x4)0.f;

    int aRow = tid >> 2, aS = tid & 3;
    u32 aSw = aRow * 32 + SW(aS, aRow);
    int gAr = m0 + aRow; if (gAr >= M) gAr = M - 1;
    const u16* gA = A1 + (size_t)gAr * 128 + aS * 8;
    int bRow[2], bS[2]; u32 bSw[2];
    #pragma unroll
    for (int j = 0; j < 2; j++) {
        int idx = tid + j * 512;
        bRow[j] = idx >> 2; bS[j] = idx & 3;
        bSw[j] = bRow[j] * 32 + SW(bS[j], bRow[j]);
    }

    uint4 rA, rB0, rB1;

    // ---------------- phase 1: K=128 over A1/W1 ----------------
    if (tid < 256) rA = *(const uint4*)gA;
    rB0 = *(const uint4*)(B1 + (size_t)bRow[0] * 128 + bS[0] * 8);
    rB1 = *(const uint4*)(B1 + (size_t)bRow[1] * 128 + bS[1] * 8);
    if (tid < 256) *(uint4*)(&sA[0][aSw]) = rA;
    *(uint4*)(&sB[0][bSw[0]]) = rB0;
    *(uint4*)(&sB[0][bSw[1]]) = rB1;
    __syncthreads();

    #pragma unroll
    for (int kb = 0; kb < 4; kb++) {
        int cur = kb & 1;
        if (kb < 3) {
            if (tid < 256) rA = *(const uint4*)(gA + (kb + 1) * 32);
            rB0 = *(const uint4*)(B1 + (size_t)bRow[0] * 128 + (kb + 1) * 32 + bS[0] * 8);
            rB1 = *(const uint4*)(B1 + (size_t)bRow[1] * 128 + (kb + 1) * 32 + bS[1] * 8);
        }
        bf16x8 a0 = *(const bf16x8*)(&sA[cur][ao[0]]);
        bf16x8 a1 = *(const bf16x8*)(&sA[cur][ao[1]]);
        bf16x8 a2 = *(const bf16x8*)(&sA[cur][ao[2]]);
        bf16x8 a3 = *(const bf16x8*)(&sA[cur][ao[3]]);
        bf16x8 h0 = *(const bf16x8*)(&sB[cur][bo[0]]);
        bf16x8 h1 = *(const bf16x8*)(&sB[cur][bo[1]]);
        MFMA_STEP(a0, a1, a2, a3, h0, h1);
        if (kb < 3) {
            int nxt = cur ^ 1;
            if (tid < 256) *(uint4*)(&sA[nxt][aSw]) = rA;
            *(uint4*)(&sB[nxt][bSw[0]]) = rB0;
            *(uint4*)(&sB[nxt][bSw[1]]) = rB1;
        }
        __syncthreads();
    }

    rB0 = *(const uint4*)(B23 + (size_t)bRow[0] * 256 + bS[0] * 8);
    rB1 = *(const uint4*)(B23 + (size_t)bRow[1] * 256 + bS[1] * 8);

    // epilogue 1: +b1, relu -> sH (bf16)
    {
        float b1c[2];
        #pragma unroll
        for (int nf = 0; nf < 2; nf++) b1c[nf] = b1[wid * 32 + nf * 16 + r16];
        int rbase = sl * 4;
        #pragma unroll
        for (int mf = 0; mf < 4; mf++)
            #pragma unroll
            for (int j = 0; j < 4; j++) {
                int r = mf * 16 + rbase + j;
                #pragma unroll
                for (int nf = 0; nf < 2; nf++) {
                    int c = wid * 32 + nf * 16 + r16;
                    sH[r * 264 + c] = f2bf(fmaxf(acc[mf][nf][j] + b1c[nf], 0.f));
                }
            }
        #pragma unroll
        for (int a = 0; a < 4; a++)
            #pragma unroll
            for (int b = 0; b < 2; b++) acc[a][b] = (f32x4)0.f;
    }
    *(uint4*)(&sB[0][bSw[0]]) = rB0;
    *(uint4*)(&sB[0][bSw[1]]) = rB1;
    __syncthreads();

    // ---------------- phase 2: K=256 over sH(H1)/W23 ----------------
    #pragma unroll
    for (int kb = 0; kb < 8; kb++) {
        int cur = kb & 1;
        if (kb < 7) {
            rB0 = *(const uint4*)(B23 + (size_t)bRow[0] * 256 + (kb + 1) * 32 + bS[0] * 8);
            rB1 = *(const uint4*)(B23 + (size_t)bRow[1] * 256 + (kb + 1) * 32 + bS[1] * 8);
        }
        bf16x8 a0 = *(const bf16x8*)(sH + (0 * 16 + r16) * 264 + kb * 32 + k8);
        bf16x8 a1 = *(const bf16x8*)(sH + (1 * 16 + r16) * 264 + kb * 32 + k8);
        bf16x8 a2 = *(const bf16x8*)(sH + (2 * 16 + r16) * 264 + kb * 32 + k8);
        bf16x8 a3 = *(const bf16x8*)(sH + (3 * 16 + r16) * 264 + kb * 32 + k8);
        bf16x8 h0 = *(const bf16x8*)(&sB[cur][bo[0]]);
        bf16x8 h1 = *(const bf16x8*)(&sB[cur][bo[1]]);
        MFMA_STEP(a0, a1, a2, a3, h0, h1);
        if (kb < 7) {
            int nxt = cur ^ 1;
            *(uint4*)(&sB[nxt][bSw[0]]) = rB0;
            *(uint4*)(&sB[nxt][bSw[1]]) = rB1;
        }
        __syncthreads();
    }

    // epilogue 2: Z = acc + c23 -> global (bf16)
    {
        float cc[2];
        #pragma unroll
        for (int nf = 0; nf < 2; nf++) cc[nf] = c23[wid * 32 + nf * 16 + r16];
        int rbase = sl * 4;
        #pragma unroll
        for (int mf = 0; mf < 4; mf++)
            #pragma unroll
            for (int j = 0; j < 4; j++) {
                int gr = m0 + mf * 16 + rbase + j;
                if (gr < M) {
                    #pragma unroll
                    for (int nf = 0; nf < 2; nf++) {
                        int gc = wid * 32 + nf * 16 + r16;
                        Z[(size_t)gr * 256 + gc] = f2bf(acc[mf][nf][j] + cc[nf]);
                    }
                }
            }
    }
}

extern "C" void kernel_launch(void* const* d_in, const int* in_sizes, int n_in,
                              void* d_out, int out_size, void* d_ws, size_t ws_size,
                              hipStream_t stream) {
    const float* feats = (const float*)d_in[0];
    const int*   src   = (const int*)d_in[1];
    const int*   dst   = (const int*)d_in[2];
    const float* W1    = (const float*)d_in[3];
    const float* b1    = (const float*)d_in[4];
    const float* W2    = (const float*)d_in[5];
    const float* b2    = (const float*)d_in[6];
    const float* Wd1   = (const float*)d_in[7];
    const float* bd1   = (const float*)d_in[8];
    const float* Wd2   = (const float*)d_in[9];
    const float* bd2   = (const float*)d_in[10];
    float* out = (float*)d_out;

    char* base = (char*)d_ws;
    size_t off = 0;
    int* cnt = (int*)(base + off); off += (size_t)NN * 4;
    int* ell = (int*)(base + off); off += (size_t)NN * MAXD * 4;   // 12.8 MB
    u16* WT1   = (u16*)(base + off); off += (size_t)FEAT * 256 * 2;
    u16* WT23  = (u16*)(base + off); off += (size_t)HID * 256 * 2;
    float* c23 = (float*)(base + off); off += 256 * 4;
    off = (off + 255) & ~(size_t)255;
    u16* featsbf = (u16*)(base + off); off += (size_t)NN * FEAT * 2;
    u16* A1      = (u16*)(base + off); off += (size_t)NN * FEAT * 2;
    u16* Zbf     = (u16*)(base + off); off += (size_t)NN * HID * 2;

    // --- degree counts zero + one-pass ELL fill merged with prep (r15 proven) ---
    hipMemsetAsync(cnt, 0, (size_t)NN * 4, stream);
    prep_fill_k<<<NB_FILL + NB_CVT + NB_W1, 256, 0, stream>>>(
        src, dst, cnt, ell, feats, W1, featsbf, WT1);

    // W23 = W2@Wd1, c23 = b2@Wd1 (dedicated LDS-tiled small GEMM)
    w23_k<<<64, 256, 0, stream>>>(W2, Wd1, b2, WT23, c23);

    // layer 1 aggregate (d=128)
    aggregate_bf_k<FEAT><<<(NN + 3) / 4, 256, 0, stream>>>(featsbf, cnt, ell, A1);

    // fused gemm1+relu+gemm23: A1 -> Z = relu(A1@W1+b1)@(W2@Wd1) + b2@Wd1
    fused_gemm12_k<<<(NN + 63) / 64, 512, 0, stream>>>(A1, WT1, b1, WT23, c23,
                                                       Zbf, NN);

    // agg2 on Z + decoder epilogue -> out
    agg2_dec_k<<<(NN + 3) / 4, 256, 0, stream>>>(Zbf, cnt, ell, bd1, Wd2, bd2, out);
}

// Round 18
// 150.609 us; speedup vs baseline: 1.2061x; 1.2061x over previous
//
#include <hip/hip_runtime.h>
#include <type_traits>

#define NN 50000
#define NE 600000
#define FEAT 128
#define HID 256
#define MAXD 64   // ELL width; max in-degree of Poisson(12) over 50k nodes ~35

typedef float v4f __attribute__((ext_vector_type(4)));
typedef float f32x4 __attribute__((ext_vector_type(4)));
typedef __bf16 bf16x8 __attribute__((ext_vector_type(8)));
using u16 = unsigned short;
using u32 = unsigned int;
typedef u16 u16x4 __attribute__((ext_vector_type(4)));
typedef u16 u16x8 __attribute__((ext_vector_type(8)));

__device__ __forceinline__ u16 f2bf(float f) {
    u32 u = __builtin_bit_cast(u32, f);
    u += 0x7fffu + ((u >> 16) & 1u);   // RNE
    return (u16)(u >> 16);
}
__device__ __forceinline__ float bf2f(u16 h) {
    u32 u = ((u32)h) << 16;
    return __builtin_bit_cast(float, u);
}

// ------- merged prep: W23/c23 FIRST (latency tail hides under FILL/CVT),
//         then ELL fill + feats cvt + W1^T.  (r15 structure, reordered grid.) -------
#define NB_W23 257            // 256 W23 k-rows + 1 c23
#define NB_FILL 2344          // (NE+255)/256
#define NB_CVT 6250           // NN*FEAT/4/256
#define NB_W1  128
__global__ __launch_bounds__(256) void prep_fill_k(const int* __restrict__ src,
                                                   const int* __restrict__ dst,
                                                   int* __restrict__ cnt,
                                                   int* __restrict__ ell,
                                                   const float* __restrict__ feats,
                                                   const float* __restrict__ W1,
                                                   const float* __restrict__ W2,
                                                   const float* __restrict__ Wd1,
                                                   const float* __restrict__ b2,
                                                   u16* __restrict__ featsbf,
                                                   u16* __restrict__ WT1,
                                                   u16* __restrict__ WT23,
                                                   float* __restrict__ c23) {
    int b = blockIdx.x, t = threadIdx.x;
    if (b < NB_W23 - 1) {
        // W23[k][n] = sum_j W2[k][j] * Wd1[j][n]; store transposed WT23[n][k]
        int k = b;                    // row of W2
        int n = t;                    // col of Wd1
        const float* w2row = W2 + (size_t)k * 256;
        float acc = 0.f;
        #pragma unroll 8
        for (int j = 0; j < 256; j++) acc += w2row[j] * Wd1[(size_t)j * 256 + n];
        WT23[(size_t)n * 256 + k] = f2bf(acc);
        return;
    }
    if (b == NB_W23 - 1) {
        // c23[n] = sum_j b2[j] * Wd1[j][n]
        int n = t;
        float acc = 0.f;
        #pragma unroll 8
        for (int j = 0; j < 256; j++) acc += b2[j] * Wd1[(size_t)j * 256 + n];
        c23[n] = acc;
        return;
    }
    b -= NB_W23;
    if (b < NB_FILL) {
        int e = b * 256 + t;
        if (e < NE) {
            int d = dst[e];
            int p = atomicAdd(&cnt[d], 1);
            if (p < MAXD) ell[(size_t)d * MAXD + p] = src[e];
        }
        return;
    }
    b -= NB_FILL;
    if (b < NB_CVT) {
        int i = b * 256 + t;
        v4f v = *(const v4f*)(feats + (size_t)i * 4);
        u16x4 o;
        #pragma unroll
        for (int j = 0; j < 4; j++) o[j] = f2bf(v[j]);
        *(u16x4*)(featsbf + (size_t)i * 4) = o;
    } else {
        int idx = (b - NB_CVT) * 256 + t;
        int k = idx >> 8, n = idx & 255;
        WT1[(size_t)n * 128 + k] = f2bf(W1[idx]);
    }
}

// ------- agg1 (proven gather core, ELL indexing) -------
template <int D>
__global__ __launch_bounds__(256) void aggregate_bf_k(const u16* __restrict__ x,
                                                      const int* __restrict__ cnt,
                                                      const int* __restrict__ ell,
                                                      u16* __restrict__ o) {
    constexpr int LPG = (D == 256) ? 32 : 16;
    constexpr int G = 64 / LPG;
    int wave = threadIdx.x >> 6;
    int lane = threadIdx.x & 63;
    int v = blockIdx.x * 4 + wave;
    if (v >= NN) return;
    int g  = lane / LPG;
    int li = lane & (LPG - 1);
    size_t coff = (size_t)li * 8;
    int deg = cnt[v]; if (deg > MAXD) deg = MAXD;
    int cntv = deg + 1;
    const int* cols = ell + (size_t)v * MAXD;
    float acc[8];
    #pragma unroll
    for (int i = 0; i < 8; i++) acc[i] = 0.f;
    int base = 0;
    #pragma unroll 4
    for (; base + G <= cntv; base += G) {
        int idx = base + g;
        int row = (idx < deg) ? cols[idx] : v;
        u16x8 r = *(const u16x8*)(x + (size_t)row * D + coff);
        #pragma unroll
        for (int i = 0; i < 8; i++) acc[i] += bf2f(r[i]);
    }
    if (base + g < cntv) {
        int idx = base + g;
        int row = (idx < deg) ? cols[idx] : v;
        u16x8 r = *(const u16x8*)(x + (size_t)row * D + coff);
        #pragma unroll
        for (int i = 0; i < 8; i++) acc[i] += bf2f(r[i]);
    }
    #pragma unroll
    for (int i = 0; i < 8; i++) {
        acc[i] += __shfl_xor(acc[i], 32, 64);
        if (G == 4) acc[i] += __shfl_xor(acc[i], 16, 64);
    }
    if (lane < LPG) {
        float inv = 1.0f / (float)cntv;
        u16x8 O;
        #pragma unroll
        for (int i = 0; i < 8; i++) O[i] = f2bf(acc[i] * inv);
        *(u16x8*)(o + (size_t)v * D + coff) = O;
    }
}

// ------- agg2 + full decoder epilogue (per-wave, no barrier, no MFMA) -------
// Z = H1@W23 + c23 precomputed; out[v] = relu(agg(Z)[v] + bd1) . wd2 + bd2.
__global__ __launch_bounds__(256) void agg2_dec_k(const u16* __restrict__ x,  // Z bf16
                                                  const int* __restrict__ cnt,
                                                  const int* __restrict__ ell,
                                                  const float* __restrict__ bd1,
                                                  const float* __restrict__ wd2,
                                                  const float* __restrict__ bd2,
                                                  float* __restrict__ out) {
    int wave = threadIdx.x >> 6;
    int lane = threadIdx.x & 63;
    int v = blockIdx.x * 4 + wave;
    if (v >= NN) return;
    int g  = lane >> 5;          // 2 edges in flight
    int li = lane & 31;
    size_t coff = (size_t)li * 8;
    int deg = cnt[v]; if (deg > MAXD) deg = MAXD;
    int cntv = deg + 1;
    const int* cols = ell + (size_t)v * MAXD;
    float acc[8];
    #pragma unroll
    for (int i = 0; i < 8; i++) acc[i] = 0.f;
    int base = 0;
    #pragma unroll 4
    for (; base + 2 <= cntv; base += 2) {
        int idx = base + g;
        int row = (idx < deg) ? cols[idx] : v;
        u16x8 r = *(const u16x8*)(x + (size_t)row * 256 + coff);
        #pragma unroll
        for (int i = 0; i < 8; i++) acc[i] += bf2f(r[i]);
    }
    if (base + g < cntv) {
        int idx = base + g;
        int row = (idx < deg) ? cols[idx] : v;
        u16x8 r = *(const u16x8*)(x + (size_t)row * 256 + coff);
        #pragma unroll
        for (int i = 0; i < 8; i++) acc[i] += bf2f(r[i]);
    }
    #pragma unroll
    for (int i = 0; i < 8; i++) acc[i] += __shfl_xor(acc[i], 32, 64);

    float inv = 1.0f / (float)cntv;
    v4f b0 = *(const v4f*)(bd1 + li * 8);
    v4f b1 = *(const v4f*)(bd1 + li * 8 + 4);
    v4f w0 = *(const v4f*)(wd2 + li * 8);
    v4f w1 = *(const v4f*)(wd2 + li * 8 + 4);
    float p = 0.f;
    #pragma unroll
    for (int i = 0; i < 4; i++) p += fmaxf(acc[i] * inv + b0[i], 0.f) * w0[i];
    #pragma unroll
    for (int i = 0; i < 4; i++) p += fmaxf(acc[i + 4] * inv + b1[i], 0.f) * w1[i];
    p += __shfl_xor(p, 1, 64);
    p += __shfl_xor(p, 2, 64);
    p += __shfl_xor(p, 4, 64);
    p += __shfl_xor(p, 8, 64);
    p += __shfl_xor(p, 16, 64);
    if (lane == 0) out[v] = p + bd2[0];
}

#define MFMA_BF16 __builtin_amdgcn_mfma_f32_16x16x32_bf16
#define SW(s, r) (((s) ^ (((r) >> 1) & 3)) * 8)

#define MFMA_STEP(pa0, pa1, pa2, pa3, ph0, ph1)              \
    do {                                                     \
        acc[0][0] = MFMA_BF16(pa0, ph0, acc[0][0], 0, 0, 0); \
        acc[0][1] = MFMA_BF16(pa0, ph1, acc[0][1], 0, 0, 0); \
        acc[1][0] = MFMA_BF16(pa1, ph0, acc[1][0], 0, 0, 0); \
        acc[1][1] = MFMA_BF16(pa1, ph1, acc[1][1], 0, 0, 0); \
        acc[2][0] = MFMA_BF16(pa2, ph0, acc[2][0], 0, 0, 0); \
        acc[2][1] = MFMA_BF16(pa2, ph1, acc[2][1], 0, 0, 0); \
        acc[3][0] = MFMA_BF16(pa3, ph0, acc[3][0], 0, 0, 0); \
        acc[3][1] = MFMA_BF16(pa3, ph1, acc[3][1], 0, 0, 0); \
    } while (0)

// ------- FUSED gemm1+gemm23: Z = relu(A1@W1+b1) @ W23 + c23 (bf16 out) -------
// BM=64, 512 thr = 8 waves over N=256 (wave 64x32). reg-dbuf staging both phases.
__global__ __launch_bounds__(512, 4) void fused_gemm12_k(const u16* __restrict__ A1,
                                                         const u16* __restrict__ B1,
                                                         const float* __restrict__ b1,
                                                         const u16* __restrict__ B23,
                                                         const float* __restrict__ c23,
                                                         u16* __restrict__ Z, int M) {
    __shared__ __attribute__((aligned(16))) u16 sA[2][64 * 32];
    __shared__ __attribute__((aligned(16))) u16 sB[2][256 * 32];
    __shared__ __attribute__((aligned(16))) u16 sH[64 * 264];

    int tid = threadIdx.x;
    int wid = tid >> 6, lane = tid & 63;
    int m0 = blockIdx.x * 64;
    int r16 = lane & 15, sl = lane >> 4, k8 = sl * 8;

    u32 ao[4], bo[2];
    #pragma unroll
    for (int mf = 0; mf < 4; mf++) {
        int ar = mf * 16 + r16;
        ao[mf] = ar * 32 + SW(sl, ar);
    }
    #pragma unroll
    for (int nf = 0; nf < 2; nf++) {
        int bc = wid * 32 + nf * 16 + r16;
        bo[nf] = bc * 32 + SW(sl, bc);
    }

    f32x4 acc[4][2];
    #pragma unroll
    for (int a = 0; a < 4; a++)
        #pragma unroll
        for (int b = 0; b < 2; b++) acc[a][b] = (f32x4)0.f;

    int aRow = tid >> 2, aS = tid & 3;
    u32 aSw = aRow * 32 + SW(aS, aRow);
    int gAr = m0 + aRow; if (gAr >= M) gAr = M - 1;
    const u16* gA = A1 + (size_t)gAr * 128 + aS * 8;
    int bRow[2], bS[2]; u32 bSw[2];
    #pragma unroll
    for (int j = 0; j < 2; j++) {
        int idx = tid + j * 512;
        bRow[j] = idx >> 2; bS[j] = idx & 3;
        bSw[j] = bRow[j] * 32 + SW(bS[j], bRow[j]);
    }

    uint4 rA, rB0, rB1;

    // ---------------- phase 1: K=128 over A1/W1 ----------------
    if (tid < 256) rA = *(const uint4*)gA;
    rB0 = *(const uint4*)(B1 + (size_t)bRow[0] * 128 + bS[0] * 8);
    rB1 = *(const uint4*)(B1 + (size_t)bRow[1] * 128 + bS[1] * 8);
    if (tid < 256) *(uint4*)(&sA[0][aSw]) = rA;
    *(uint4*)(&sB[0][bSw[0]]) = rB0;
    *(uint4*)(&sB[0][bSw[1]]) = rB1;
    __syncthreads();

    #pragma unroll
    for (int kb = 0; kb < 4; kb++) {
        int cur = kb & 1;
        if (kb < 3) {
            if (tid < 256) rA = *(const uint4*)(gA + (kb + 1) * 32);
            rB0 = *(const uint4*)(B1 + (size_t)bRow[0] * 128 + (kb + 1) * 32 + bS[0] * 8);
            rB1 = *(const uint4*)(B1 + (size_t)bRow[1] * 128 + (kb + 1) * 32 + bS[1] * 8);
        }
        bf16x8 a0 = *(const bf16x8*)(&sA[cur][ao[0]]);
        bf16x8 a1 = *(const bf16x8*)(&sA[cur][ao[1]]);
        bf16x8 a2 = *(const bf16x8*)(&sA[cur][ao[2]]);
        bf16x8 a3 = *(const bf16x8*)(&sA[cur][ao[3]]);
        bf16x8 h0 = *(const bf16x8*)(&sB[cur][bo[0]]);
        bf16x8 h1 = *(const bf16x8*)(&sB[cur][bo[1]]);
        MFMA_STEP(a0, a1, a2, a3, h0, h1);
        if (kb < 3) {
            int nxt = cur ^ 1;
            if (tid < 256) *(uint4*)(&sA[nxt][aSw]) = rA;
            *(uint4*)(&sB[nxt][bSw[0]]) = rB0;
            *(uint4*)(&sB[nxt][bSw[1]]) = rB1;
        }
        __syncthreads();
    }

    rB0 = *(const uint4*)(B23 + (size_t)bRow[0] * 256 + bS[0] * 8);
    rB1 = *(const uint4*)(B23 + (size_t)bRow[1] * 256 + bS[1] * 8);

    // epilogue 1: +b1, relu -> sH (bf16)
    {
        float b1c[2];
        #pragma unroll
        for (int nf = 0; nf < 2; nf++) b1c[nf] = b1[wid * 32 + nf * 16 + r16];
        int rbase = sl * 4;
        #pragma unroll
        for (int mf = 0; mf < 4; mf++)
            #pragma unroll
            for (int j = 0; j < 4; j++) {
                int r = mf * 16 + rbase + j;
                #pragma unroll
                for (int nf = 0; nf < 2; nf++) {
                    int c = wid * 32 + nf * 16 + r16;
                    sH[r * 264 + c] = f2bf(fmaxf(acc[mf][nf][j] + b1c[nf], 0.f));
                }
            }
        #pragma unroll
        for (int a = 0; a < 4; a++)
            #pragma unroll
            for (int b = 0; b < 2; b++) acc[a][b] = (f32x4)0.f;
    }
    *(uint4*)(&sB[0][bSw[0]]) = rB0;
    *(uint4*)(&sB[0][bSw[1]]) = rB1;
    __syncthreads();

    // ---------------- phase 2: K=256 over sH(H1)/W23 ----------------
    #pragma unroll
    for (int kb = 0; kb < 8; kb++) {
        int cur = kb & 1;
        if (kb < 7) {
            rB0 = *(const uint4*)(B23 + (size_t)bRow[0] * 256 + (kb + 1) * 32 + bS[0] * 8);
            rB1 = *(const uint4*)(B23 + (size_t)bRow[1] * 256 + (kb + 1) * 32 + bS[1] * 8);
        }
        bf16x8 a0 = *(const bf16x8*)(sH + (0 * 16 + r16) * 264 + kb * 32 + k8);
        bf16x8 a1 = *(const bf16x8*)(sH + (1 * 16 + r16) * 264 + kb * 32 + k8);
        bf16x8 a2 = *(const bf16x8*)(sH + (2 * 16 + r16) * 264 + kb * 32 + k8);
        bf16x8 a3 = *(const bf16x8*)(sH + (3 * 16 + r16) * 264 + kb * 32 + k8);
        bf16x8 h0 = *(const bf16x8*)(&sB[cur][bo[0]]);
        bf16x8 h1 = *(const bf16x8*)(&sB[cur][bo[1]]);
        MFMA_STEP(a0, a1, a2, a3, h0, h1);
        if (kb < 7) {
            int nxt = cur ^ 1;
            *(uint4*)(&sB[nxt][bSw[0]]) = rB0;
            *(uint4*)(&sB[nxt][bSw[1]]) = rB1;
        }
        __syncthreads();
    }

    // epilogue 2: Z = acc + c23 -> global (bf16)
    {
        float cc[2];
        #pragma unroll
        for (int nf = 0; nf < 2; nf++) cc[nf] = c23[wid * 32 + nf * 16 + r16];
        int rbase = sl * 4;
        #pragma unroll
        for (int mf = 0; mf < 4; mf++)
            #pragma unroll
            for (int j = 0; j < 4; j++) {
                int gr = m0 + mf * 16 + rbase + j;
                if (gr < M) {
                    #pragma unroll
                    for (int nf = 0; nf < 2; nf++) {
                        int gc = wid * 32 + nf * 16 + r16;
                        Z[(size_t)gr * 256 + gc] = f2bf(acc[mf][nf][j] + cc[nf]);
                    }
                }
            }
    }
}

extern "C" void kernel_launch(void* const* d_in, const int* in_sizes, int n_in,
                              void* d_out, int out_size, void* d_ws, size_t ws_size,
                              hipStream_t stream) {
    const float* feats = (const float*)d_in[0];
    const int*   src   = (const int*)d_in[1];
    const int*   dst   = (const int*)d_in[2];
    const float* W1    = (const float*)d_in[3];
    const float* b1    = (const float*)d_in[4];
    const float* W2    = (const float*)d_in[5];
    const float* b2    = (const float*)d_in[6];
    const float* Wd1   = (const float*)d_in[7];
    const float* bd1   = (const float*)d_in[8];
    const float* Wd2   = (const float*)d_in[9];
    const float* bd2   = (const float*)d_in[10];
    float* out = (float*)d_out;

    char* base = (char*)d_ws;
    size_t off = 0;
    int* cnt = (int*)(base + off); off += (size_t)NN * 4;
    int* ell = (int*)(base + off); off += (size_t)NN * MAXD * 4;   // 12.8 MB
    u16* WT1   = (u16*)(base + off); off += (size_t)FEAT * 256 * 2;
    u16* WT23  = (u16*)(base + off); off += (size_t)HID * 256 * 2;
    float* c23 = (float*)(base + off); off += 256 * 4;
    off = (off + 255) & ~(size_t)255;
    u16* featsbf = (u16*)(base + off); off += (size_t)NN * FEAT * 2;
    u16* A1      = (u16*)(base + off); off += (size_t)NN * FEAT * 2;
    u16* Zbf     = (u16*)(base + off); off += (size_t)NN * HID * 2;

    // --- degree counts zero + one-pass ELL fill merged with prep (W23 first) ---
    hipMemsetAsync(cnt, 0, (size_t)NN * 4, stream);
    prep_fill_k<<<NB_W23 + NB_FILL + NB_CVT + NB_W1, 256, 0, stream>>>(
        src, dst, cnt, ell, feats, W1, W2, Wd1, b2, featsbf, WT1, WT23, c23);

    // layer 1 aggregate (d=128)
    aggregate_bf_k<FEAT><<<(NN + 3) / 4, 256, 0, stream>>>(featsbf, cnt, ell, A1);

    // fused gemm1+relu+gemm23: A1 -> Z = relu(A1@W1+b1)@(W2@Wd1) + b2@Wd1
    fused_gemm12_k<<<(NN + 63) / 64, 512, 0, stream>>>(A1, WT1, b1, WT23, c23,
                                                       Zbf, NN);

    // agg2 on Z + decoder epilogue -> out
    agg2_dec_k<<<(NN + 3) / 4, 256, 0, stream>>>(Zbf, cnt, ell, bd1, Wd2, bd2, out);
}